// Round 1
// baseline (547.690 us; speedup 1.0000x reference)
//
#include <hip/hip_runtime.h>
#include <hip/hip_bf16.h>
#include <cmath>

// ---------------- types / helpers ----------------
typedef __attribute__((ext_vector_type(8))) short short8;   // 8 x bf16 (4 VGPRs)
typedef __attribute__((ext_vector_type(4))) float floatx4;  // MFMA C/D

typedef __attribute__((address_space(1))) unsigned int u32g;
typedef __attribute__((address_space(3))) unsigned int u32l;

__device__ __forceinline__ void async16(void* lds, const void* g) {
  // global -> LDS direct DMA, 16B per lane, dest = wave-uniform base + lane*16
  __builtin_amdgcn_global_load_lds((const u32g*)g, (u32l*)lds, 16, 0, 0);
}

__device__ __forceinline__ float bf2f(__hip_bfloat16 v) { return __bfloat162float(v); }
__device__ __forceinline__ __hip_bfloat16 f2bfr(float v) { return __float2bfloat16(v); }

#define TOK 2048     // B*L
#define DMODEL 1024
#define DINNER 2048
#define DFFN 4096
#define NSTATE 16
#define DTRANK 64

// ---------------- fp32 -> bf16 converts ----------------
__global__ void k_f2bf(const float* __restrict__ in, __hip_bfloat16* __restrict__ out, int n) {
  int i = blockIdx.x * 256 + threadIdx.x;
  int stride = gridDim.x * 256;
  for (; i < n; i += stride) out[i] = f2bfr(in[i]);
}

__global__ void k_f2bf_pad(const float* __restrict__ in, __hip_bfloat16* __restrict__ out,
                           int n_src, int n_dst) {
  int i = blockIdx.x * 256 + threadIdx.x;
  int stride = gridDim.x * 256;
  for (; i < n_dst; i += stride) out[i] = (i < n_src) ? f2bfr(in[i]) : f2bfr(0.f);
}

// ---------------- causal depthwise conv (K=4) + silu ----------------
__global__ __launch_bounds__(256) void k_conv_silu(const float* __restrict__ xz,
                                                   const float* __restrict__ w,
                                                   const float* __restrict__ b,
                                                   __hip_bfloat16* __restrict__ xc) {
  int idx = blockIdx.x * 256 + threadIdx.x;  // TOK*DINNER threads
  int d = idx & (DINNER - 1);
  int t = idx >> 11;
  int l = t & 1023;
  const float* xp = xz + (size_t)t * (2 * DINNER) + d;  // x = first DINNER cols of xz
  float acc = b[d];
  float4 wv = *(const float4*)&w[d * 4];
  if (l >= 3) acc += wv.x * xp[-3 * (2 * DINNER)];
  if (l >= 2) acc += wv.y * xp[-2 * (2 * DINNER)];
  if (l >= 1) acc += wv.z * xp[-1 * (2 * DINNER)];
  acc += wv.w * xp[0];
  float s = acc / (1.f + __expf(-acc));  // silu
  xc[(size_t)t * DINNER + d] = f2bfr(s);
}

// ---------------- MFMA GEMM: C[m,n] = sum_k A[m,k] * W[n,k] ----------------
// A: M x K bf16 row-major; B(weights): N x K bf16 row-major.
// 128x128 block tile, BK=32, 4 waves (2x2 of 64x64), mfma 16x16x32 bf16.
// MODE epilogues:
//  0: outF[m*N+n] = v
//  1: x_proj: if n<96 outF[m*96+n]=v ; if n<64 outB[m*64+n]=bf16(v)
//  2: v = softplus(v + bias[n]) -> outF
//  3: v += res[m*N+n] -> outF
//  4: v = gelu_exact(v + bias[n]) -> outB (bf16)
//  5: v += bias[n] + res[m*N+n] -> outF
template <int MODE>
__global__ __launch_bounds__(256) void k_gemm(const __hip_bfloat16* __restrict__ A,
                                              const __hip_bfloat16* __restrict__ B,
                                              float* __restrict__ outF,
                                              __hip_bfloat16* __restrict__ outB,
                                              const float* __restrict__ bias,
                                              const float* __restrict__ res,
                                              int M, int N, int K) {
  __shared__ __hip_bfloat16 As[128][32];
  __shared__ __hip_bfloat16 Bs[128][32];
  const int tid = threadIdx.x;
  const int wave = tid >> 6;
  const int lane = tid & 63;
  const int m0 = blockIdx.x * 128;
  const int n0 = blockIdx.y * 128;
  const int wr = wave >> 1, wc = wave & 1;

  floatx4 acc[4][4] = {};

  // staging: each wave covers rows [wave*32, wave*32+32) in two 16-row issues
  const int srow = wave * 32 + (lane >> 2);
  const int scol = (lane & 3) * 8;
  const __hip_bfloat16* gA = A + (size_t)(m0 + srow) * K + scol;
  const __hip_bfloat16* gB = B + (size_t)(n0 + srow) * K + scol;
  __hip_bfloat16* lA0 = &As[wave * 32][0];
  __hip_bfloat16* lA1 = &As[wave * 32 + 16][0];
  __hip_bfloat16* lB0 = &Bs[wave * 32][0];
  __hip_bfloat16* lB1 = &Bs[wave * 32 + 16][0];

  const int lr = lane & 15;
  const int lq = lane >> 4;

  for (int k0 = 0; k0 < K; k0 += 32) {
    __syncthreads();  // all waves done reading LDS of previous iter
    async16(lA0, gA + k0);
    async16(lA1, gA + k0 + (size_t)16 * K);
    async16(lB0, gB + k0);
    async16(lB1, gB + k0 + (size_t)16 * K);
    __syncthreads();  // compiler drains vmcnt(0) before barrier -> LDS valid

    short8 af[4], bfr[4];
#pragma unroll
    for (int mt = 0; mt < 4; mt++)
      af[mt] = *(const short8*)&As[wr * 64 + mt * 16 + lr][lq * 8];
#pragma unroll
    for (int nt = 0; nt < 4; nt++)
      bfr[nt] = *(const short8*)&Bs[wc * 64 + nt * 16 + lr][lq * 8];
#pragma unroll
    for (int mt = 0; mt < 4; mt++)
#pragma unroll
      for (int nt = 0; nt < 4; nt++)
        acc[mt][nt] = __builtin_amdgcn_mfma_f32_16x16x32_bf16(af[mt], bfr[nt], acc[mt][nt], 0, 0, 0);
  }

  // epilogue: D layout col=lane&15, row=(lane>>4)*4+reg
#pragma unroll
  for (int mt = 0; mt < 4; mt++) {
#pragma unroll
    for (int nt = 0; nt < 4; nt++) {
      int n = n0 + wc * 64 + nt * 16 + lr;
#pragma unroll
      for (int r = 0; r < 4; r++) {
        int m = m0 + wr * 64 + mt * 16 + lq * 4 + r;
        float v = acc[mt][nt][r];
        size_t o = (size_t)m * N + n;
        if (MODE == 0) {
          outF[o] = v;
        } else if (MODE == 1) {
          if (n < 96) outF[(size_t)m * 96 + n] = v;
          if (n < 64) outB[(size_t)m * 64 + n] = f2bfr(v);
        } else if (MODE == 2) {
          v += bias[n];
          v = (v > 20.f) ? v : log1pf(expf(v));
          outF[o] = v;
        } else if (MODE == 3) {
          outF[o] = v + res[o];
        } else if (MODE == 4) {
          v += bias[n];
          v = 0.5f * v * (1.f + erff(v * 0.70710678118654752f));
          outB[o] = f2bfr(v);
        } else if (MODE == 5) {
          outF[o] = v + bias[n] + res[o];
        }
      }
    }
  }
}

// ---------------- selective scan, chunked (16 chunks of 64) ----------------
// phase A: local scan from h=0 per chunk; emit final local h and sum(dt)
__global__ __launch_bounds__(256) void k_scan1(const float* __restrict__ dt,
                                               const __hip_bfloat16* __restrict__ xc,
                                               const float* __restrict__ xdbl,
                                               const float* __restrict__ A_log,
                                               float* __restrict__ hloc,
                                               float* __restrict__ dtsum) {
  int bid = blockIdx.x;  // 256 blocks = b(2) * c(16) * dg(8)
  int dg = bid & 7;
  int c = (bid >> 3) & 15;
  int b = bid >> 7;
  int d = dg * 256 + threadIdx.x;
  __shared__ float Bsh[64][16];
  for (int j = threadIdx.x; j < 64 * 16; j += 256) {
    int i = j >> 4, n = j & 15;
    Bsh[i][n] = xdbl[(size_t)(b * 1024 + c * 64 + i) * 96 + 64 + n];
  }
  __syncthreads();
  float Av[16];
#pragma unroll
  for (int n = 0; n < 16; n++) Av[n] = -__expf(A_log[d * 16 + n]);
  float h[16];
#pragma unroll
  for (int n = 0; n < 16; n++) h[n] = 0.f;
  float ds = 0.f;
  int tbase = b * 1024 + c * 64;
  for (int i = 0; i < 64; i++) {
    size_t t = tbase + i;
    float dtv = dt[t * DINNER + d];
    float xv = bf2f(xc[t * DINNER + d]);
    float dtx = dtv * xv;
    ds += dtv;
#pragma unroll
    for (int n = 0; n < 16; n++) h[n] = __expf(dtv * Av[n]) * h[n] + dtx * Bsh[i][n];
  }
  size_t o = (size_t)(b * 16 + c) * DINNER + d;
#pragma unroll
  for (int n = 0; n < 16; n++) hloc[o * 16 + n] = h[n];
  dtsum[o] = ds;
}

// phase B: sequential stitch over 16 chunks; chunk decay = exp(A * sum_dt)
__global__ __launch_bounds__(256) void k_stitch(const float* __restrict__ A_log,
                                                const float* __restrict__ hloc,
                                                const float* __restrict__ dtsum,
                                                float* __restrict__ hin) {
  int idx = blockIdx.x * 256 + threadIdx.x;  // 4096 = b*DINNER
  int d = idx & (DINNER - 1);
  int b = idx >> 11;
  float Av[16];
#pragma unroll
  for (int n = 0; n < 16; n++) Av[n] = -__expf(A_log[d * 16 + n]);
  float h[16];
#pragma unroll
  for (int n = 0; n < 16; n++) h[n] = 0.f;
  for (int c = 0; c < 16; c++) {
    size_t o = (size_t)(b * 16 + c) * DINNER + d;
#pragma unroll
    for (int n = 0; n < 16; n++) hin[o * 16 + n] = h[n];
    float p = dtsum[o];
#pragma unroll
    for (int n = 0; n < 16; n++) h[n] = __expf(Av[n] * p) * h[n] + hloc[o * 16 + n];
  }
}

// phase C: re-scan from stitched state, emit y -> (+x*D) -> *silu(z) -> bf16
__global__ __launch_bounds__(256) void k_scan2(const float* __restrict__ dt,
                                               const __hip_bfloat16* __restrict__ xc,
                                               const float* __restrict__ xdbl,
                                               const float* __restrict__ A_log,
                                               const float* __restrict__ hin,
                                               const float* __restrict__ Dv,
                                               const float* __restrict__ xz,
                                               __hip_bfloat16* __restrict__ ygate) {
  int bid = blockIdx.x;
  int dg = bid & 7;
  int c = (bid >> 3) & 15;
  int b = bid >> 7;
  int d = dg * 256 + threadIdx.x;
  __shared__ float Bsh[64][16];
  __shared__ float Csh[64][16];
  for (int j = threadIdx.x; j < 64 * 16; j += 256) {
    int i = j >> 4, n = j & 15;
    size_t base = (size_t)(b * 1024 + c * 64 + i) * 96;
    Bsh[i][n] = xdbl[base + 64 + n];
    Csh[i][n] = xdbl[base + 80 + n];
  }
  __syncthreads();
  float Av[16];
#pragma unroll
  for (int n = 0; n < 16; n++) Av[n] = -__expf(A_log[d * 16 + n]);
  size_t o = (size_t)(b * 16 + c) * DINNER + d;
  float h[16];
#pragma unroll
  for (int n = 0; n < 16; n++) h[n] = hin[o * 16 + n];
  float Dd = Dv[d];
  int tbase = b * 1024 + c * 64;
  for (int i = 0; i < 64; i++) {
    size_t t = tbase + i;
    float dtv = dt[t * DINNER + d];
    float xv = bf2f(xc[t * DINNER + d]);
    float dtx = dtv * xv;
    float y = 0.f;
#pragma unroll
    for (int n = 0; n < 16; n++) {
      h[n] = __expf(dtv * Av[n]) * h[n] + dtx * Bsh[i][n];
      y += h[n] * Csh[i][n];
    }
    y += xv * Dd;
    float zv = xz[t * (2 * DINNER) + DINNER + d];
    float g = zv / (1.f + __expf(-zv));
    ygate[t * DINNER + d] = f2bfr(y * g);
  }
}

// ---------------- rmsnorm (per token row of DMODEL) ----------------
__global__ __launch_bounds__(256) void k_rmsnorm(const float* __restrict__ in,
                                                 const float* __restrict__ w,
                                                 float* __restrict__ outF,
                                                 __hip_bfloat16* __restrict__ outB) {
  int t = blockIdx.x;
  const float* row = in + (size_t)t * DMODEL;
  float s = 0.f;
  for (int i = threadIdx.x; i < DMODEL; i += 256) {
    float v = row[i];
    s += v * v;
  }
#pragma unroll
  for (int o = 32; o > 0; o >>= 1) s += __shfl_down(s, o);
  __shared__ float red[4];
  if ((threadIdx.x & 63) == 0) red[threadIdx.x >> 6] = s;
  __syncthreads();
  s = red[0] + red[1] + red[2] + red[3];
  float r = rsqrtf(s * (1.f / DMODEL) + 1e-6f);
  for (int i = threadIdx.x; i < DMODEL; i += 256) {
    float v = row[i] * r * w[i];
    if (outF) outF[(size_t)t * DMODEL + i] = v;
    if (outB) outB[(size_t)t * DMODEL + i] = f2bfr(v);
  }
}

// ---------------- host launcher ----------------
extern "C" void kernel_launch(void* const* d_in, const int* in_sizes, int n_in,
                              void* d_out, int out_size, void* d_ws, size_t ws_size,
                              hipStream_t stream) {
  const float* Z = (const float*)d_in[0];
  const float* in_proj = (const float*)d_in[1];
  const float* conv_w = (const float*)d_in[2];
  const float* conv_b = (const float*)d_in[3];
  const float* x_proj = (const float*)d_in[4];
  const float* dt_projw = (const float*)d_in[5];
  const float* dt_projb = (const float*)d_in[6];
  const float* A_log = (const float*)d_in[7];
  const float* Dvec = (const float*)d_in[8];
  const float* out_proj = (const float*)d_in[9];
  const float* mlp_w1 = (const float*)d_in[10];
  const float* mlp_b1 = (const float*)d_in[11];
  const float* mlp_w2 = (const float*)d_in[12];
  const float* mlp_b2 = (const float*)d_in[13];
  const float* norm1_w = (const float*)d_in[14];
  float* out = (float*)d_out;

  char* ws = (char*)d_ws;
  size_t off = 0;
  auto alloc = [&](size_t bytes) {
    char* p = ws + off;
    off += (bytes + 255) & ~(size_t)255;
    return p;
  };

  __hip_bfloat16* w_in_bf = (__hip_bfloat16*)alloc((size_t)4096 * 1024 * 2);
  __hip_bfloat16* w_xp_bf = (__hip_bfloat16*)alloc((size_t)128 * 2048 * 2);  // padded 96->128
  __hip_bfloat16* w_dt_bf = (__hip_bfloat16*)alloc((size_t)2048 * 64 * 2);
  __hip_bfloat16* w_out_bf = (__hip_bfloat16*)alloc((size_t)1024 * 2048 * 2);
  __hip_bfloat16* w_m1_bf = (__hip_bfloat16*)alloc((size_t)4096 * 1024 * 2);
  __hip_bfloat16* w_m2_bf = (__hip_bfloat16*)alloc((size_t)1024 * 4096 * 2);
  __hip_bfloat16* Z_bf = (__hip_bfloat16*)alloc((size_t)TOK * DMODEL * 2);
  char* xz_region = alloc((size_t)TOK * 4096 * 4);  // 32 MB, reused after scan
  float* xz_f = (float*)xz_region;
  __hip_bfloat16* xc_bf = (__hip_bfloat16*)alloc((size_t)TOK * DINNER * 2);
  float* xdbl_f = (float*)alloc((size_t)TOK * 96 * 4);
  __hip_bfloat16* dtin_bf = (__hip_bfloat16*)alloc((size_t)TOK * 64 * 2);
  char* dt_region = alloc((size_t)TOK * DINNER * 4);  // 16 MB, reused after scan
  float* dt_f = (float*)dt_region;
  __hip_bfloat16* ygate_bf = (__hip_bfloat16*)alloc((size_t)TOK * DINNER * 2);
  float* hloc = (float*)alloc((size_t)2 * 16 * DINNER * 16 * 4);
  float* dtsum = (float*)alloc((size_t)2 * 16 * DINNER * 4);
  float* hin = (float*)alloc((size_t)2 * 16 * DINNER * 16 * 4);

  // aliases into regions that are dead after the scan
  float* resid1_f = (float*)(xz_region + 0);
  float* zmam_f = (float*)(xz_region + 8388608);
  __hip_bfloat16* zmam_bf = (__hip_bfloat16*)(xz_region + 16777216);
  float* resid2_f = (float*)(xz_region + 20971520);
  __hip_bfloat16* h_bf = (__hip_bfloat16*)dt_region;

  dim3 blk(256);

  // converts
  k_f2bf<<<4096, blk, 0, stream>>>(in_proj, w_in_bf, 4096 * 1024);
  k_f2bf<<<512, blk, 0, stream>>>(dt_projw, w_dt_bf, 2048 * 64);
  k_f2bf<<<4096, blk, 0, stream>>>(out_proj, w_out_bf, 1024 * 2048);
  k_f2bf<<<4096, blk, 0, stream>>>(mlp_w1, w_m1_bf, 4096 * 1024);
  k_f2bf<<<4096, blk, 0, stream>>>(mlp_w2, w_m2_bf, 1024 * 4096);
  k_f2bf<<<4096, blk, 0, stream>>>(Z, Z_bf, TOK * DMODEL);
  k_f2bf_pad<<<1024, blk, 0, stream>>>(x_proj, w_xp_bf, 96 * 2048, 128 * 2048);

  // in_proj: xz = Z @ in_proj^T  (2048 x 4096)
  k_gemm<0><<<dim3(16, 32), blk, 0, stream>>>(Z_bf, w_in_bf, xz_f, nullptr, nullptr, nullptr,
                                              TOK, 4096, 1024);
  // conv + silu on x half
  k_conv_silu<<<(TOK * DINNER) / 256, blk, 0, stream>>>(xz_f, conv_w, conv_b, xc_bf);
  // x_proj: x_dbl = xc @ x_proj^T (N padded to 128; fp32 96 cols + bf16 dt 64 cols)
  k_gemm<1><<<dim3(16, 1), blk, 0, stream>>>(xc_bf, w_xp_bf, xdbl_f, dtin_bf, nullptr, nullptr,
                                             TOK, 128, 2048);
  // dt_proj + softplus: dt (2048 x 2048)
  k_gemm<2><<<dim3(16, 16), blk, 0, stream>>>(dtin_bf, w_dt_bf, dt_f, nullptr, dt_projb, nullptr,
                                              TOK, DINNER, 64);
  // selective scan
  k_scan1<<<256, blk, 0, stream>>>(dt_f, xc_bf, xdbl_f, A_log, hloc, dtsum);
  k_stitch<<<16, blk, 0, stream>>>(A_log, hloc, dtsum, hin);
  k_scan2<<<256, blk, 0, stream>>>(dt_f, xc_bf, xdbl_f, A_log, hin, Dvec, xz_f, ygate_bf);
  // out_proj + residual(Z)
  k_gemm<3><<<dim3(16, 8), blk, 0, stream>>>(ygate_bf, w_out_bf, resid1_f, nullptr, nullptr, Z,
                                             TOK, DMODEL, DINNER);
  // rmsnorm -> Z_mam (fp32 + bf16)
  k_rmsnorm<<<TOK, blk, 0, stream>>>(resid1_f, norm1_w, zmam_f, zmam_bf);
  // mlp1 + bias + exact gelu -> h (bf16)
  k_gemm<4><<<dim3(16, 32), blk, 0, stream>>>(zmam_bf, w_m1_bf, nullptr, h_bf, mlp_b1, nullptr,
                                              TOK, DFFN, DMODEL);
  // mlp2 + bias + residual(Z_mam)
  k_gemm<5><<<dim3(16, 8), blk, 0, stream>>>(h_bf, w_m2_bf, resid2_f, nullptr, mlp_b2, zmam_f,
                                             TOK, DMODEL, DFFN);
  // final rmsnorm -> out
  k_rmsnorm<<<TOK, blk, 0, stream>>>(resid2_f, norm1_w, out, nullptr);
}

// Round 2
// 429.985 us; speedup vs baseline: 1.2737x; 1.2737x over previous
//
#include <hip/hip_runtime.h>
#include <hip/hip_bf16.h>
#include <cmath>

// ---------------- types / helpers ----------------
typedef __attribute__((ext_vector_type(8))) short short8;   // 8 x bf16 (4 VGPRs)
typedef __attribute__((ext_vector_type(4))) float floatx4;  // MFMA C/D

typedef __attribute__((address_space(1))) unsigned int u32g;
typedef __attribute__((address_space(3))) unsigned int u32l;

__device__ __forceinline__ void async16(void* lds, const void* g) {
  // global -> LDS direct DMA, 16B per lane, dest = wave-uniform base + lane*16
  __builtin_amdgcn_global_load_lds((const u32g*)g, (u32l*)lds, 16, 0, 0);
}

__device__ __forceinline__ float bf2f(__hip_bfloat16 v) { return __bfloat162float(v); }
__device__ __forceinline__ __hip_bfloat16 f2bfr(float v) { return __float2bfloat16(v); }
__device__ __forceinline__ unsigned short f2bfu(float v) {
  __hip_bfloat16 h = __float2bfloat16(v);
  return *(unsigned short*)&h;
}

#define TOK 2048     // B*L
#define DMODEL 1024
#define DINNER 2048
#define DFFN 4096

// ---------------- fp32 -> bf16 converts (vectorized) ----------------
__global__ __launch_bounds__(256) void k_f2bf_v4(const float* __restrict__ in,
                                                 unsigned short* __restrict__ out, int n) {
  int i = (blockIdx.x * 256 + threadIdx.x) * 4;
  if (i >= n) return;
  float4 v = *(const float4*)(in + i);
  ushort4 o;
  o.x = f2bfu(v.x); o.y = f2bfu(v.y); o.z = f2bfu(v.z); o.w = f2bfu(v.w);
  *(ushort4*)(out + i) = o;
}

__global__ __launch_bounds__(256) void k_f2bf_pad_v4(const float* __restrict__ in,
                                                     unsigned short* __restrict__ out,
                                                     int n_src, int n_dst) {
  int i = (blockIdx.x * 256 + threadIdx.x) * 4;
  if (i >= n_dst) return;
  ushort4 o;
  if (i < n_src) {  // n_src divisible by 4
    float4 v = *(const float4*)(in + i);
    o.x = f2bfu(v.x); o.y = f2bfu(v.y); o.z = f2bfu(v.z); o.w = f2bfu(v.w);
  } else {
    o.x = o.y = o.z = o.w = 0;
  }
  *(ushort4*)(out + i) = o;
}

// ---------------- causal depthwise conv (K=4) + silu ----------------
__global__ __launch_bounds__(256) void k_conv_silu(const float* __restrict__ xz,
                                                   const float* __restrict__ w,
                                                   const float* __restrict__ b,
                                                   __hip_bfloat16* __restrict__ xc) {
  int idx = blockIdx.x * 256 + threadIdx.x;  // TOK*DINNER threads
  int d = idx & (DINNER - 1);
  int t = idx >> 11;
  int l = t & 1023;
  const float* xp = xz + (size_t)t * (2 * DINNER) + d;  // x = first DINNER cols of xz
  float acc = b[d];
  float4 wv = *(const float4*)&w[d * 4];
  if (l >= 3) acc += wv.x * xp[-3 * (2 * DINNER)];
  if (l >= 2) acc += wv.y * xp[-2 * (2 * DINNER)];
  if (l >= 1) acc += wv.z * xp[-1 * (2 * DINNER)];
  acc += wv.w * xp[0];
  float s = acc / (1.f + __expf(-acc));  // silu
  xc[(size_t)t * DINNER + d] = f2bfr(s);
}

// ---------------- MFMA GEMM: C[m,n] = sum_k A[m,k] * W[n,k] ----------------
// A: M x Kfull bf16 row-major; B(weights): N x Kfull bf16 row-major.
// BM x BN block tile, BK=32, 4 waves (2x2), mfma 16x16x32 bf16.
// Double-buffered LDS: stage tile k+1 (async global_load_lds) BEFORE computing
// tile k; the single barrier at loop top drains vmcnt AFTER compute overlapped
// the staging latency. Critical at low blocks/CU where no other waves hide it.
// MODE epilogues:
//  0: outF[m*N+n] = v
//  2: v = softplus(v + bias[n]) -> outF
//  3: v += res[m*N+n] -> outF
//  4: v = gelu_exact(v + bias[n]) -> outB (bf16)
//  5: v += bias[n] + res[m*N+n] -> outF
//  6: split-K partial: outF[z*M*N + m*N+n] = v  (k range = [z*Kc, (z+1)*Kc))
template <int BM, int BN, int MODE>
__global__ __launch_bounds__(256) void k_gemm(const __hip_bfloat16* __restrict__ A,
                                              const __hip_bfloat16* __restrict__ B,
                                              float* __restrict__ outF,
                                              __hip_bfloat16* __restrict__ outB,
                                              const float* __restrict__ bias,
                                              const float* __restrict__ res,
                                              int M, int N, int Kfull, int Kc) {
  constexpr int WTM = BM / 32;  // 16-wide m-tiles per wave
  constexpr int WTN = BN / 32;
  __shared__ __hip_bfloat16 As[2][BM][32];
  __shared__ __hip_bfloat16 Bs[2][BN][32];
  const int tid = threadIdx.x;
  const int wave = tid >> 6;
  const int lane = tid & 63;
  const int m0 = blockIdx.x * BM;
  const int n0 = blockIdx.y * BN;
  const int kbase = blockIdx.z * Kc;
  const int wr = wave >> 1, wc = wave & 1;

  floatx4 acc[WTM][WTN] = {};

  // staging source pattern: lane covers row lane>>2, cols (lane&3)*8 of a 16x32 chunk
  const int srow = lane >> 2;
  const int scol = (lane & 3) * 8;
  const __hip_bfloat16* gA = A + (size_t)(m0 + srow) * Kfull + scol + kbase;
  const __hip_bfloat16* gB = B + (size_t)(n0 + srow) * Kfull + scol + kbase;

  const int lr = lane & 15;
  const int lq = lane >> 4;

  constexpr int nChA = BM / 16;
  constexpr int nChT = (BM + BN) / 16;

  auto stage = [&](int buf, int k0) {
#pragma unroll
    for (int ch = 0; ch < nChT; ch += 4) {
      int c = ch + wave;
      if (c < nChT) {
        if (c < nChA)
          async16(&As[buf][c * 16][0], gA + (size_t)c * 16 * Kfull + k0);
        else
          async16(&Bs[buf][(c - nChA) * 16][0], gB + (size_t)(c - nChA) * 16 * Kfull + k0);
      }
    }
  };

  stage(0, 0);
  int cur = 0;
  for (int k0 = 0; k0 < Kc; k0 += 32) {
    __syncthreads();  // drains vmcnt(0): staged buffer valid; prev compute's LDS reads done
    if (k0 + 32 < Kc) stage(cur ^ 1, k0 + 32);

    short8 af[WTM], bfr[WTN];
#pragma unroll
    for (int mt = 0; mt < WTM; mt++)
      af[mt] = *(const short8*)&As[cur][wr * 16 * WTM + mt * 16 + lr][lq * 8];
#pragma unroll
    for (int nt = 0; nt < WTN; nt++)
      bfr[nt] = *(const short8*)&Bs[cur][wc * 16 * WTN + nt * 16 + lr][lq * 8];
#pragma unroll
    for (int mt = 0; mt < WTM; mt++)
#pragma unroll
      for (int nt = 0; nt < WTN; nt++)
        acc[mt][nt] = __builtin_amdgcn_mfma_f32_16x16x32_bf16(af[mt], bfr[nt], acc[mt][nt], 0, 0, 0);
    cur ^= 1;
  }

  // epilogue: D layout col=lane&15, row=(lane>>4)*4+reg
#pragma unroll
  for (int mt = 0; mt < WTM; mt++) {
#pragma unroll
    for (int nt = 0; nt < WTN; nt++) {
      int n = n0 + wc * 16 * WTN + nt * 16 + lr;
#pragma unroll
      for (int r = 0; r < 4; r++) {
        int m = m0 + wr * 16 * WTM + mt * 16 + lq * 4 + r;
        float v = acc[mt][nt][r];
        size_t o = (size_t)m * N + n;
        if (MODE == 0) {
          outF[o] = v;
        } else if (MODE == 2) {
          v += bias[n];
          v = (v > 20.f) ? v : log1pf(expf(v));
          outF[o] = v;
        } else if (MODE == 3) {
          outF[o] = v + res[o];
        } else if (MODE == 4) {
          v += bias[n];
          v = 0.5f * v * (1.f + erff(v * 0.70710678118654752f));
          outB[o] = f2bfr(v);
        } else if (MODE == 5) {
          outF[o] = v + bias[n] + res[o];
        } else if (MODE == 6) {
          outF[(size_t)blockIdx.z * M * N + o] = v;
        }
      }
    }
  }
}

// x_proj split-K finalize: sum 8 partial slices, split into fp32 (96) + bf16 dt (64)
__global__ __launch_bounds__(256) void k_xproj_fin(const float* __restrict__ part,
                                                   float* __restrict__ xdbl,
                                                   __hip_bfloat16* __restrict__ dtin) {
  int idx = blockIdx.x * 256 + threadIdx.x;  // TOK*128
  int n = idx & 127;
  int m = idx >> 7;
  float s = 0.f;
#pragma unroll
  for (int z = 0; z < 8; z++) s += part[(size_t)z * TOK * 128 + idx];
  if (n < 96) xdbl[(size_t)m * 96 + n] = s;
  if (n < 64) dtin[(size_t)m * 64 + n] = f2bfr(s);
}

// ---------------- selective scan, chunked (16 chunks of 64) ----------------
__global__ __launch_bounds__(256) void k_scan1(const float* __restrict__ dt,
                                               const __hip_bfloat16* __restrict__ xc,
                                               const float* __restrict__ xdbl,
                                               const float* __restrict__ A_log,
                                               float* __restrict__ hloc,
                                               float* __restrict__ dtsum) {
  int bid = blockIdx.x;  // 256 blocks = b(2) * c(16) * dg(8)
  int dg = bid & 7;
  int c = (bid >> 3) & 15;
  int b = bid >> 7;
  int d = dg * 256 + threadIdx.x;
  __shared__ float Bsh[64][16];
  for (int j = threadIdx.x; j < 64 * 16; j += 256) {
    int i = j >> 4, n = j & 15;
    Bsh[i][n] = xdbl[(size_t)(b * 1024 + c * 64 + i) * 96 + 64 + n];
  }
  __syncthreads();
  float Av[16];
#pragma unroll
  for (int n = 0; n < 16; n++) Av[n] = -__expf(A_log[d * 16 + n]);
  float h[16];
#pragma unroll
  for (int n = 0; n < 16; n++) h[n] = 0.f;
  float ds = 0.f;
  int tbase = b * 1024 + c * 64;
  for (int i = 0; i < 64; i++) {
    size_t t = tbase + i;
    float dtv = dt[t * DINNER + d];
    float xv = bf2f(xc[t * DINNER + d]);
    float dtx = dtv * xv;
    ds += dtv;
#pragma unroll
    for (int n = 0; n < 16; n++) h[n] = __expf(dtv * Av[n]) * h[n] + dtx * Bsh[i][n];
  }
  size_t o = (size_t)(b * 16 + c) * DINNER + d;
#pragma unroll
  for (int n = 0; n < 16; n++) hloc[o * 16 + n] = h[n];
  dtsum[o] = ds;
}

__global__ __launch_bounds__(256) void k_stitch(const float* __restrict__ A_log,
                                                const float* __restrict__ hloc,
                                                const float* __restrict__ dtsum,
                                                float* __restrict__ hin) {
  int idx = blockIdx.x * 256 + threadIdx.x;  // 4096 = b*DINNER
  int d = idx & (DINNER - 1);
  int b = idx >> 11;
  float Av[16];
#pragma unroll
  for (int n = 0; n < 16; n++) Av[n] = -__expf(A_log[d * 16 + n]);
  float h[16];
#pragma unroll
  for (int n = 0; n < 16; n++) h[n] = 0.f;
  for (int c = 0; c < 16; c++) {
    size_t o = (size_t)(b * 16 + c) * DINNER + d;
#pragma unroll
    for (int n = 0; n < 16; n++) hin[o * 16 + n] = h[n];
    float p = dtsum[o];
#pragma unroll
    for (int n = 0; n < 16; n++) h[n] = __expf(Av[n] * p) * h[n] + hloc[o * 16 + n];
  }
}

__global__ __launch_bounds__(256) void k_scan2(const float* __restrict__ dt,
                                               const __hip_bfloat16* __restrict__ xc,
                                               const float* __restrict__ xdbl,
                                               const float* __restrict__ A_log,
                                               const float* __restrict__ hin,
                                               const float* __restrict__ Dv,
                                               const float* __restrict__ xz,
                                               __hip_bfloat16* __restrict__ ygate) {
  int bid = blockIdx.x;
  int dg = bid & 7;
  int c = (bid >> 3) & 15;
  int b = bid >> 7;
  int d = dg * 256 + threadIdx.x;
  __shared__ float Bsh[64][16];
  __shared__ float Csh[64][16];
  for (int j = threadIdx.x; j < 64 * 16; j += 256) {
    int i = j >> 4, n = j & 15;
    size_t base = (size_t)(b * 1024 + c * 64 + i) * 96;
    Bsh[i][n] = xdbl[base + 64 + n];
    Csh[i][n] = xdbl[base + 80 + n];
  }
  __syncthreads();
  float Av[16];
#pragma unroll
  for (int n = 0; n < 16; n++) Av[n] = -__expf(A_log[d * 16 + n]);
  size_t o = (size_t)(b * 16 + c) * DINNER + d;
  float h[16];
#pragma unroll
  for (int n = 0; n < 16; n++) h[n] = hin[o * 16 + n];
  float Dd = Dv[d];
  int tbase = b * 1024 + c * 64;
  for (int i = 0; i < 64; i++) {
    size_t t = tbase + i;
    float dtv = dt[t * DINNER + d];
    float xv = bf2f(xc[t * DINNER + d]);
    float dtx = dtv * xv;
    float y = 0.f;
#pragma unroll
    for (int n = 0; n < 16; n++) {
      h[n] = __expf(dtv * Av[n]) * h[n] + dtx * Bsh[i][n];
      y += h[n] * Csh[i][n];
    }
    y += xv * Dd;
    float zv = xz[t * (2 * DINNER) + DINNER + d];
    float g = zv / (1.f + __expf(-zv));
    ygate[t * DINNER + d] = f2bfr(y * g);
  }
}

// ---------------- rmsnorm (per token row of DMODEL) ----------------
__global__ __launch_bounds__(256) void k_rmsnorm(const float* __restrict__ in,
                                                 const float* __restrict__ w,
                                                 float* __restrict__ outF,
                                                 __hip_bfloat16* __restrict__ outB) {
  int t = blockIdx.x;
  const float* row = in + (size_t)t * DMODEL;
  float s = 0.f;
  for (int i = threadIdx.x; i < DMODEL; i += 256) {
    float v = row[i];
    s += v * v;
  }
#pragma unroll
  for (int o = 32; o > 0; o >>= 1) s += __shfl_down(s, o);
  __shared__ float red[4];
  if ((threadIdx.x & 63) == 0) red[threadIdx.x >> 6] = s;
  __syncthreads();
  s = red[0] + red[1] + red[2] + red[3];
  float r = rsqrtf(s * (1.f / DMODEL) + 1e-6f);
  for (int i = threadIdx.x; i < DMODEL; i += 256) {
    float v = row[i] * r * w[i];
    if (outF) outF[(size_t)t * DMODEL + i] = v;
    if (outB) outB[(size_t)t * DMODEL + i] = f2bfr(v);
  }
}

// ---------------- host launcher ----------------
extern "C" void kernel_launch(void* const* d_in, const int* in_sizes, int n_in,
                              void* d_out, int out_size, void* d_ws, size_t ws_size,
                              hipStream_t stream) {
  const float* Z = (const float*)d_in[0];
  const float* in_proj = (const float*)d_in[1];
  const float* conv_w = (const float*)d_in[2];
  const float* conv_b = (const float*)d_in[3];
  const float* x_proj = (const float*)d_in[4];
  const float* dt_projw = (const float*)d_in[5];
  const float* dt_projb = (const float*)d_in[6];
  const float* A_log = (const float*)d_in[7];
  const float* Dvec = (const float*)d_in[8];
  const float* out_proj = (const float*)d_in[9];
  const float* mlp_w1 = (const float*)d_in[10];
  const float* mlp_b1 = (const float*)d_in[11];
  const float* mlp_w2 = (const float*)d_in[12];
  const float* mlp_b2 = (const float*)d_in[13];
  const float* norm1_w = (const float*)d_in[14];
  float* out = (float*)d_out;

  char* ws = (char*)d_ws;
  size_t off = 0;
  auto alloc = [&](size_t bytes) {
    char* p = ws + off;
    off += (bytes + 255) & ~(size_t)255;
    return p;
  };

  __hip_bfloat16* w_in_bf = (__hip_bfloat16*)alloc((size_t)4096 * 1024 * 2);
  __hip_bfloat16* w_xp_bf = (__hip_bfloat16*)alloc((size_t)128 * 2048 * 2);  // padded 96->128
  __hip_bfloat16* w_dt_bf = (__hip_bfloat16*)alloc((size_t)2048 * 64 * 2);
  __hip_bfloat16* w_out_bf = (__hip_bfloat16*)alloc((size_t)1024 * 2048 * 2);
  __hip_bfloat16* w_m1_bf = (__hip_bfloat16*)alloc((size_t)4096 * 1024 * 2);
  __hip_bfloat16* w_m2_bf = (__hip_bfloat16*)alloc((size_t)1024 * 4096 * 2);
  __hip_bfloat16* Z_bf = (__hip_bfloat16*)alloc((size_t)TOK * DMODEL * 2);
  char* xz_region = alloc((size_t)TOK * 4096 * 4);  // 32 MB, reused after scan
  float* xz_f = (float*)xz_region;
  __hip_bfloat16* xc_bf = (__hip_bfloat16*)alloc((size_t)TOK * DINNER * 2);
  float* xdbl_f = (float*)alloc((size_t)TOK * 96 * 4);
  __hip_bfloat16* dtin_bf = (__hip_bfloat16*)alloc((size_t)TOK * 64 * 2);
  char* dt_region = alloc((size_t)TOK * DINNER * 4);  // 16 MB, reused after scan
  float* dt_f = (float*)dt_region;
  __hip_bfloat16* ygate_bf = (__hip_bfloat16*)alloc((size_t)TOK * DINNER * 2);
  float* hloc = (float*)alloc((size_t)2 * 16 * DINNER * 16 * 4);
  float* dtsum = (float*)alloc((size_t)2 * 16 * DINNER * 4);
  float* hin = (float*)alloc((size_t)2 * 16 * DINNER * 16 * 4);
  float* xp_part = (float*)alloc((size_t)8 * TOK * 128 * 4);  // split-K partials

  // aliases into regions that are dead after the scan
  float* resid1_f = (float*)(xz_region + 0);
  float* zmam_f = (float*)(xz_region + 8388608);
  __hip_bfloat16* zmam_bf = (__hip_bfloat16*)(xz_region + 16777216);
  float* resid2_f = (float*)(xz_region + 20971520);
  __hip_bfloat16* h_bf = (__hip_bfloat16*)dt_region;

  dim3 blk(256);

  // converts (vectorized, 4 elems/thread)
  k_f2bf_v4<<<4096, blk, 0, stream>>>(in_proj, (unsigned short*)w_in_bf, 4096 * 1024);
  k_f2bf_v4<<<128, blk, 0, stream>>>(dt_projw, (unsigned short*)w_dt_bf, 2048 * 64);
  k_f2bf_v4<<<2048, blk, 0, stream>>>(out_proj, (unsigned short*)w_out_bf, 1024 * 2048);
  k_f2bf_v4<<<4096, blk, 0, stream>>>(mlp_w1, (unsigned short*)w_m1_bf, 4096 * 1024);
  k_f2bf_v4<<<4096, blk, 0, stream>>>(mlp_w2, (unsigned short*)w_m2_bf, 1024 * 4096);
  k_f2bf_v4<<<2048, blk, 0, stream>>>(Z, (unsigned short*)Z_bf, TOK * DMODEL);
  k_f2bf_pad_v4<<<256, blk, 0, stream>>>(x_proj, (unsigned short*)w_xp_bf, 96 * 2048, 128 * 2048);

  // in_proj: xz = Z @ in_proj^T  (2048 x 4096, K=1024)
  k_gemm<128, 128, 0><<<dim3(16, 32), blk, 0, stream>>>(Z_bf, w_in_bf, xz_f, nullptr, nullptr,
                                                        nullptr, TOK, 4096, 1024, 1024);
  // conv + silu on x half
  k_conv_silu<<<(TOK * DINNER) / 256, blk, 0, stream>>>(xz_f, conv_w, conv_b, xc_bf);
  // x_proj: split-K=8 partials (2048 x 128, K=2048, chunks of 256)
  k_gemm<64, 128, 6><<<dim3(32, 1, 8), blk, 0, stream>>>(xc_bf, w_xp_bf, xp_part, nullptr,
                                                         nullptr, nullptr, TOK, 128, 2048, 256);
  k_xproj_fin<<<1024, blk, 0, stream>>>(xp_part, xdbl_f, dtin_bf);
  // dt_proj + softplus: dt (2048 x 2048, K=64)
  k_gemm<64, 128, 2><<<dim3(32, 16), blk, 0, stream>>>(dtin_bf, w_dt_bf, dt_f, nullptr, dt_projb,
                                                       nullptr, TOK, DINNER, 64, 64);
  // selective scan
  k_scan1<<<256, blk, 0, stream>>>(dt_f, xc_bf, xdbl_f, A_log, hloc, dtsum);
  k_stitch<<<16, blk, 0, stream>>>(A_log, hloc, dtsum, hin);
  k_scan2<<<256, blk, 0, stream>>>(dt_f, xc_bf, xdbl_f, A_log, hin, Dvec, xz_f, ygate_bf);
  // out_proj + residual(Z)  (2048 x 1024, K=2048)
  k_gemm<64, 64, 3><<<dim3(32, 16), blk, 0, stream>>>(ygate_bf, w_out_bf, resid1_f, nullptr,
                                                      nullptr, Z, TOK, DMODEL, DINNER, DINNER);
  // rmsnorm -> Z_mam (fp32 + bf16)
  k_rmsnorm<<<TOK, blk, 0, stream>>>(resid1_f, norm1_w, zmam_f, zmam_bf);
  // mlp1 + bias + exact gelu -> h (bf16)  (2048 x 4096, K=1024)
  k_gemm<128, 128, 4><<<dim3(16, 32), blk, 0, stream>>>(zmam_bf, w_m1_bf, nullptr, h_bf, mlp_b1,
                                                        nullptr, TOK, DFFN, DMODEL, DMODEL);
  // mlp2 + bias + residual(Z_mam)  (2048 x 1024, K=4096)
  k_gemm<64, 64, 5><<<dim3(32, 16), blk, 0, stream>>>(h_bf, w_m2_bf, resid2_f, nullptr, mlp_b2,
                                                      zmam_f, TOK, DMODEL, DFFN, DFFN);
  // final rmsnorm -> out
  k_rmsnorm<<<TOK, blk, 0, stream>>>(resid2_f, norm1_w, out, nullptr);
}